// Round 9
// baseline (321.227 us; speedup 1.0000x reference)
//
#include <hip/hip_runtime.h>
#include <hip/hip_fp16.h>

#define D_ 1024
#define C2LOG2E 2.8853900817779268f   // 2*log2(e); pre-multiplied into Wi,bi

typedef __fp16   fp16x2 __attribute__((ext_vector_type(2)));
typedef _Float16 h4 __attribute__((ext_vector_type(4)));
typedef _Float16 h8 __attribute__((ext_vector_type(8)));
typedef float    f4 __attribute__((ext_vector_type(4)));

#define MFMA32(A, B, C) __builtin_amdgcn_mfma_f32_16x16x32_f16(A, B, C, 0, 0, 0)
#define MFMA16(A, B, C) __builtin_amdgcn_mfma_f32_16x16x16f16(A, B, C, 0, 0, 0)

// ---- merged pre-pass.
// part 1 (t<12288): Wi f32[4][256][80] + bi -> h8[st][rt 16][chunk 12][p16 16],
//   PRE-SCALED by 2*log2(e). chunks 0-9 real K, 10 = [C2*bias,0x7], 11 = 0.
// part 2 (t<16384): Wo -> 16x16x16 A-frags h4[st][rt 16][lane 64], scaled by -2
//   (h = 1-2r fold: z = rowsum(Wo) + (-2Wo).r).
// part 3 (64 threads): rowsum[st][c] = sum_k Wo[st][c][k]; c>=8 -> 0.
__global__ void prep_all(const float* __restrict__ Wi, const float* __restrict__ bi,
                         const float* __restrict__ Wo,
                         h8* __restrict__ Wi16, h4* __restrict__ Wo2m,
                         float* __restrict__ rowsum) {
    int t = blockIdx.x * 256 + threadIdx.x;
    if (t < 12288) {
        int p16 = t & 15;
        int chunk = (t >> 4) % 12;
        int rt = ((t >> 4) / 12) & 15;
        int st = t / 3072;
        int r = rt * 16 + p16;
        h8 v = {0, 0, 0, 0, 0, 0, 0, 0};
        if (chunk < 10) {
            const float* s = Wi + ((size_t)(st * 256 + r) * 80 + chunk * 8);
#pragma unroll
            for (int j = 0; j < 8; ++j) v[j] = (_Float16)(C2LOG2E * s[j]);
        } else if (chunk == 10) {
            v[0] = (_Float16)(C2LOG2E * bi[st * 256 + r]);
        }
        Wi16[t] = v;
    } else if (t < 16384) {
        int u = t - 12288;
        int lane = u & 63;
        int s = (u >> 6) & 1;
        int kc = (u >> 7) & 7;
        int st = u >> 10;
        int p16 = lane & 15, q = lane >> 4;
        h4 v = {0, 0, 0, 0};
        if (p16 < 8) {
            const float* src = Wo + ((size_t)(st * 8 + p16) * 256 + kc * 32 + s * 16 + q * 4);
#pragma unroll
            for (int j = 0; j < 4; ++j) v[j] = (_Float16)(-2.f * src[j]);
        }
        Wo2m[u] = v;
    } else {
        int u = t - 16384;
        if (u < 64) {
            int st = u >> 4, c = u & 15;
            float s = 0.f;
            if (c < 8) {
                const float* src = Wo + (size_t)(st * 8 + c) * 256;
                for (int k = 0; k < 256; ++k) s += src[k];
            }
            rowsum[u] = s;
        }
    }
}

// r = sigmoid-like 1/(1+2^s) from pre-scaled s; h = 1-2r folded into GEMM2.
// Saturation via f16 specials: 2^(+big)=inf -> r=0; 2^(-big)=0 -> r=1.
__device__ __forceinline__ h4 sig4(const f4 a) {
    const __half2 ONE = __float2half2_rn(1.0f);
    union { h4 v; fp16x2 h[2]; __half2 hh[2]; } u;
    u.h[0] = __builtin_amdgcn_cvt_pkrtz(a[0], a[1]);
    u.h[1] = __builtin_amdgcn_cvt_pkrtz(a[2], a[3]);
#pragma unroll
    for (int i = 0; i < 2; ++i) {
        __half2 e = h2exp2(u.hh[i]);
        u.hh[i] = h2rcp(__hadd2(e, ONE));
    }
    return u.v;
}

// ---- main: 2 waves per row (pt halves), 8 waves/SIMD (VGPR capped at 64).
// Loop inversion keeps registers tiny: pt outer (b-frags read once per pt),
// 16 rt-phases inner streaming A-frags from L2. z double-buffered in LDS,
// one barrier per stage (cross-wave window dependency).
__global__ __launch_bounds__(256, 8) void ldrfm9(
    const float* __restrict__ x,       // [N,1024]
    const h8* __restrict__ Wi16,       // [4][16][12][16]
    const h4* __restrict__ Wo2m,       // [4][16][64]  (-2*Wo frags)
    const float* __restrict__ rowsum,  // [4][16]
    float* __restrict__ out)           // [N,1024]
{
    __shared__ h8 xr[2][136];          // per-row x ring (slot s = pair s-2)
    __shared__ h8 zb[2][2][136];       // z double-buffer rings
    __shared__ h8 cpad[8][16];         // [pt][0]=e0 (bias col), [pt][1]=0 (pad)

    const int tid = threadIdx.x;
    const int w = tid >> 6, lane = tid & 63;
    const int p16 = lane & 15, q = lane >> 4;
    const int lrow = w >> 1, half = w & 1;
    const int row = blockIdx.x * 2 + lrow;

    if (w == 0 && lane < 16) {
        h8 v = {0, 0, 0, 0, 0, 0, 0, 0};
        if ((lane & 1) == 0) v[0] = (_Float16)1.0f;
        cpad[lane >> 1][lane & 1] = v;
    }

    if (half == 0) {  // one wave fills the rings for its row
        const f4* xp = (const f4*)(x + (size_t)row * D_) + lane * 4;
        f4 v0 = xp[0], v1 = xp[1], v2 = xp[2], v3 = xp[3];
        union { h8 v; fp16x2 h[4]; } a, b;
        a.h[0] = __builtin_amdgcn_cvt_pkrtz(v0[0], v0[1]);
        a.h[1] = __builtin_amdgcn_cvt_pkrtz(v0[2], v0[3]);
        a.h[2] = __builtin_amdgcn_cvt_pkrtz(v1[0], v1[1]);
        a.h[3] = __builtin_amdgcn_cvt_pkrtz(v1[2], v1[3]);
        b.h[0] = __builtin_amdgcn_cvt_pkrtz(v2[0], v2[1]);
        b.h[1] = __builtin_amdgcn_cvt_pkrtz(v2[2], v2[3]);
        b.h[2] = __builtin_amdgcn_cvt_pkrtz(v3[0], v3[1]);
        b.h[3] = __builtin_amdgcn_cvt_pkrtz(v3[2], v3[3]);
        xr[lrow][2 * lane + 2] = a.v;    xr[lrow][2 * lane + 3] = b.v;
        zb[0][lrow][2 * lane + 2] = a.v; zb[0][lrow][2 * lane + 3] = b.v;
        if (lane == 63) {  // pairs 126,127 -> slots 0,1
            xr[lrow][0] = a.v; xr[lrow][1] = b.v;
            zb[0][lrow][0] = a.v; zb[0][lrow][1] = b.v;
        }
        if (lane == 0) {   // pairs 0,1 -> slots 130,131
            xr[lrow][130] = a.v; xr[lrow][131] = b.v;
            zb[0][lrow][130] = a.v; zb[0][lrow][131] = b.v;
        }
    }
    __syncthreads();

    // fixed per-lane pieces (byte addressing; pt_l adds +256B)
    const char* xbase = (const char*)&xr[lrow][0] + half * 1024;
    const char* b0p = xbase + (p16 + q) * 16;
    float* op = out + (size_t)row * D_ + half * 512 + p16 * 8 + q * 4;
    const f4 FZ = {0.f, 0.f, 0.f, 0.f};

#pragma unroll 1
    for (int st = 0; st < 4; ++st) {
        const h8* WiS = Wi16 + st * 3072;
        const h4* WoS = Wo2m + st * 1024;
        const f4 rs = *(const f4*)(rowsum + st * 16 + q * 4);

        const char* zcur = (const char*)&zb[st & 1][lrow][0] + half * 1024;
        char* znxt = (char*)&zb[(st + 1) & 1][lrow][0] + half * 1024;
        const char* b1p = (q == 0) ? (xbase + (p16 + 4) * 16)
                                   : (zcur + (p16 + q - 1) * 16);
        const char* b2p = (q < 2) ? (zcur + (p16 + 3 + q) * 16)
                                  : ((const char*)&cpad[half * 4][q - 2]);
        char* zw = znxt + (p16 + 2) * 16 + q * 8;

#pragma unroll 1
        for (int ptl = 0; ptl < 4; ++ptl) {
            h8 b0 = *(const h8*)(b0p + ptl * 256);
            h8 b1 = *(const h8*)(b1p + ptl * 256);
            h8 b2 = *(const h8*)(b2p + ptl * 256);
            f4 acc = rs;

            const h8* Ap = WiS + q * 16 + p16;   // rt=0; +192 per phase
            const h4* Bp = WoS + lane;           // +64 per phase
#pragma unroll 2
            for (int ph = 0; ph < 16; ++ph) {
                h8 A0 = Ap[0], A1 = Ap[64], A2 = Ap[128];
                h4 Bf = Bp[0];
                f4 a = MFMA32(A0, b0, FZ);
                a = MFMA32(A1, b1, a);
                a = MFMA32(A2, b2, a);
                h4 r = sig4(a);
                acc = MFMA16(Bf, r, acc);
                Ap += 192;
                Bp += 64;
            }

            if (st < 3) {
                if (q < 2) {
                    union { h4 v; fp16x2 h[2]; } zv;
                    zv.h[0] = __builtin_amdgcn_cvt_pkrtz(acc[0], acc[1]);
                    zv.h[1] = __builtin_amdgcn_cvt_pkrtz(acc[2], acc[3]);
                    *(h4*)(zw + ptl * 256) = zv.v;
                    if (half == 0 && ptl == 0 && p16 < 2)     // pairs 0,1 -> 130,131
                        *(h4*)(zw + ptl * 256 + 2048) = zv.v;
                    if (half == 1 && ptl == 3 && p16 >= 14)   // pairs 126,127 -> 0,1
                        *(h4*)(zw + ptl * 256 - 2048) = zv.v;
                }
            } else {
                if (q < 2) *(f4*)(op + ptl * 128) = acc;
            }
        }
        if (st < 3) __syncthreads();   // all z-writes land before next stage reads
    }
}

extern "C" void kernel_launch(void* const* d_in, const int* in_sizes, int n_in,
                              void* d_out, int out_size, void* d_ws, size_t ws_size,
                              hipStream_t stream) {
    const float* x  = (const float*)d_in[0];
    const float* Wi = (const float*)d_in[1];
    const float* bi = (const float*)d_in[2];
    const float* Wo = (const float*)d_in[3];
    float* out = (float*)d_out;

    h8* Wi16 = (h8*)d_ws;                           // 12288 h8 = 196608 B
    h4* Wo2m = (h4*)((char*)d_ws + 196608);         // 4096 h4  = 32768 B
    float* rowsum = (float*)((char*)d_ws + 229376); // 64 f32   = 256 B

    prep_all<<<65, 256, 0, stream>>>(Wi, bi, Wo, Wi16, Wo2m, rowsum);

    int nrows = in_sizes[0] / D_;                   // 4096
    ldrfm9<<<nrows / 2, 256, 0, stream>>>(x, Wi16, Wo2m, rowsum, out);
}

// Round 10
// 207.784 us; speedup vs baseline: 1.5460x; 1.5460x over previous
//
#include <hip/hip_runtime.h>
#include <hip/hip_fp16.h>

#define D_ 1024
#define C2LOG2E 2.8853900817779268f   // 2*log2(e); pre-multiplied into Wi,bi

typedef __fp16   fp16x2 __attribute__((ext_vector_type(2)));
typedef _Float16 h4 __attribute__((ext_vector_type(4)));
typedef _Float16 h8 __attribute__((ext_vector_type(8)));
typedef float    f4 __attribute__((ext_vector_type(4)));

#define MFMA32(A, B, C) __builtin_amdgcn_mfma_f32_16x16x32_f16(A, B, C, 0, 0, 0)
#define MFMA16(A, B, C) __builtin_amdgcn_mfma_f32_16x16x16f16(A, B, C, 0, 0, 0)

// ---- merged pre-pass.
// part 1 (t<12288): Wi f32[4][256][80] + bi -> h8[st][rt 16][chunk 12][p16 16],
//   PRE-SCALED by 2*log2(e). chunks 0-9 real K, 10 = [C2*bias,0x7], 11 = 0.
// part 2 (t<16384): Wo -> 16x16x16 A-frags h4[st][kc 8][s 2][lane 64], scaled
//   by -2 (h = 1-2r fold: z = rowsum(Wo) + (-2Wo).r).
// part 3 (64 threads): rowsum[st][c] = sum_k Wo[st][c][k]; c>=8 -> 0.
__global__ void prep_all(const float* __restrict__ Wi, const float* __restrict__ bi,
                         const float* __restrict__ Wo,
                         h8* __restrict__ Wi16, h4* __restrict__ Wo2m,
                         float* __restrict__ rowsum) {
    int t = blockIdx.x * 256 + threadIdx.x;
    if (t < 12288) {
        int p16 = t & 15;
        int chunk = (t >> 4) % 12;
        int rt = ((t >> 4) / 12) & 15;
        int st = t / 3072;
        int r = rt * 16 + p16;
        h8 v = {0, 0, 0, 0, 0, 0, 0, 0};
        if (chunk < 10) {
            const float* s = Wi + ((size_t)(st * 256 + r) * 80 + chunk * 8);
#pragma unroll
            for (int j = 0; j < 8; ++j) v[j] = (_Float16)(C2LOG2E * s[j]);
        } else if (chunk == 10) {
            v[0] = (_Float16)(C2LOG2E * bi[st * 256 + r]);
        }
        Wi16[t] = v;
    } else if (t < 16384) {
        int u = t - 12288;
        int lane = u & 63;
        int s = (u >> 6) & 1;
        int kc = (u >> 7) & 7;
        int st = u >> 10;
        int p16 = lane & 15, q = lane >> 4;
        h4 v = {0, 0, 0, 0};
        if (p16 < 8) {
            const float* src = Wo + ((size_t)(st * 8 + p16) * 256 + kc * 32 + s * 16 + q * 4);
#pragma unroll
            for (int j = 0; j < 4; ++j) v[j] = (_Float16)(-2.f * src[j]);
        }
        Wo2m[u] = v;
    } else {
        int u = t - 16384;
        if (u < 64) {
            int st = u >> 4, c = u & 15;
            float s = 0.f;
            if (c < 8) {
                const float* src = Wo + (size_t)(st * 8 + c) * 256;
                for (int k = 0; k < 256; ++k) s += src[k];
            }
            rowsum[u] = s;
        }
    }
}

// r = 1/(1+2^s) from pre-scaled s; h = 1-2r folded into GEMM2 (acc init =
// rowsum, B operand = r). Saturation via f16 specials: 2^(+big)=inf -> r=0;
// 2^(-big)=0 -> r=1. cvt_pkrtz clamps overflow to +-65504 (finite).
__device__ __forceinline__ h4 sig4(const f4 a) {
    const __half2 ONE = __float2half2_rn(1.0f);
    union { h4 v; fp16x2 h[2]; __half2 hh[2]; } u;
    u.h[0] = __builtin_amdgcn_cvt_pkrtz(a[0], a[1]);
    u.h[1] = __builtin_amdgcn_cvt_pkrtz(a[2], a[3]);
#pragma unroll
    for (int i = 0; i < 2; ++i) {
        __half2 e = h2exp2(u.hh[i]);
        u.hh[i] = h2rcp(__hadd2(e, ONE));
    }
    return u.v;
}

// ---- main: 1 wave = 1 row; no barriers, no cross-lane H exchange.
// launch_bounds(256,2): grid gives 16 waves/CU (4/SIMD); VGPR should stay
// <=128 for 4 waves/SIMD. kc unroll 2 lets the scheduler hoist kc+1's
// A-frag loads over kc's pt work (hide ~200cyc L2 latency).
__global__ __launch_bounds__(256, 2) void ldrfm10(
    const float* __restrict__ x,       // [N,1024]
    const h8* __restrict__ Wi16,       // [4][16][12][16]
    const h4* __restrict__ Wo2m,       // [4][8][2][64]  (-2*Wo frags)
    const float* __restrict__ rowsum,  // [4][16]
    float* __restrict__ out)           // [N,1024]
{
    // rings replicated so windows never wrap: slot s holds pair (s-2) mod 128
    __shared__ h8 xr[4][136];
    __shared__ h8 zr[4][136];
    __shared__ h8 cpad[8][16];      // [pt][0]=e0 (bias col), [pt][1]=0 (K-pad)

    const int tid = threadIdx.x;
    const int w = tid >> 6, lane = tid & 63;
    const int p16 = lane & 15, q = lane >> 4;
    const int row = blockIdx.x * 4 + w;

    if (lane < 16) {
        h8 v = {0, 0, 0, 0, 0, 0, 0, 0};
        if ((lane & 1) == 0) v[0] = (_Float16)1.0f;
        cpad[lane >> 1][lane & 1] = v;
    }

    // load + convert own row -> x ring and z ring (z starts as x), with replicas
    {
        const f4* xp = (const f4*)(x + (size_t)row * D_) + lane * 4;
        f4 v0 = xp[0], v1 = xp[1], v2 = xp[2], v3 = xp[3];
        union { h8 v; fp16x2 h[4]; } a, b;
        a.h[0] = __builtin_amdgcn_cvt_pkrtz(v0[0], v0[1]);
        a.h[1] = __builtin_amdgcn_cvt_pkrtz(v0[2], v0[3]);
        a.h[2] = __builtin_amdgcn_cvt_pkrtz(v1[0], v1[1]);
        a.h[3] = __builtin_amdgcn_cvt_pkrtz(v1[2], v1[3]);
        b.h[0] = __builtin_amdgcn_cvt_pkrtz(v2[0], v2[1]);
        b.h[1] = __builtin_amdgcn_cvt_pkrtz(v2[2], v2[3]);
        b.h[2] = __builtin_amdgcn_cvt_pkrtz(v3[0], v3[1]);
        b.h[3] = __builtin_amdgcn_cvt_pkrtz(v3[2], v3[3]);
        xr[w][2 * lane + 2] = a.v; xr[w][2 * lane + 3] = b.v;
        zr[w][2 * lane + 2] = a.v; zr[w][2 * lane + 3] = b.v;
        if (lane == 63) {          // pairs 126,127 -> slots 0,1
            xr[w][0] = a.v; xr[w][1] = b.v; zr[w][0] = a.v; zr[w][1] = b.v;
        }
        if (lane == 0) {           // pairs 0,1 -> slots 130,131
            xr[w][130] = a.v; xr[w][131] = b.v; zr[w][130] = a.v; zr[w][131] = b.v;
        }
    }

    // per-lane B-frag base addresses (fixed for whole kernel); pt adds +256B
    const h8* b0p = &xr[w][p16 + q];                               // chunks 0-3 (x)
    const h8* b1p = (q == 0) ? &xr[w][p16 + 4]                     // chunk 4 (x)
                             : &zr[w][p16 + q - 1];                // chunks 5-7 (z)
    const h8* b2p = (q < 2) ? &zr[w][p16 + 3 + q]                  // chunks 8-9 (z)
                            : (const h8*)&cpad[0][q - 2];          // bias / pad
    _Float16* zwp = (_Float16*)&zr[w][p16 + 2] + q * 4;
    float* op = out + (size_t)row * D_ + p16 * 8 + q * 4;

    const f4 FZ = {0.f, 0.f, 0.f, 0.f};

#pragma unroll 1
    for (int st = 0; st < 4; ++st) {
        const h8* WiS = Wi16 + st * 3072;
        const h4* WoS = Wo2m + st * 1024;
        const f4 rs = *(const f4*)(rowsum + st * 16 + q * 4);

        f4 acc2[8];
#pragma unroll
        for (int i = 0; i < 8; ++i) acc2[i] = rs;   // h=1-2r fold: init = rowsum

#pragma unroll 2
        for (int kc = 0; kc < 8; ++kc) {
            const h8* wp0 = WiS + ((2 * kc) * 12 + q) * 16 + p16;
            const h8* wp1 = WiS + ((2 * kc + 1) * 12 + q) * 16 + p16;
            h8 A00 = wp0[0], A01 = wp0[64], A02 = wp0[128];
            h8 A10 = wp1[0], A11 = wp1[64], A12 = wp1[128];
            h4 B20 = WoS[(kc * 2 + 0) * 64 + lane];
            h4 B21 = WoS[(kc * 2 + 1) * 64 + lane];

#pragma unroll
            for (int pt = 0; pt < 8; ++pt) {
                h8 b0 = *(const h8*)((const char*)b0p + pt * 256);
                h8 b1 = *(const h8*)((const char*)b1p + pt * 256);
                h8 b2 = *(const h8*)((const char*)b2p + pt * 256);
                f4 a0 = MFMA32(A00, b0, FZ);
                a0 = MFMA32(A01, b1, a0);
                a0 = MFMA32(A02, b2, a0);
                f4 a1 = MFMA32(A10, b0, FZ);
                a1 = MFMA32(A11, b1, a1);
                a1 = MFMA32(A12, b2, a1);
                h4 r0 = sig4(a0);
                h4 r1 = sig4(a1);
                acc2[pt] = MFMA16(B20, r0, acc2[pt]);
                acc2[pt] = MFMA16(B21, r1, acc2[pt]);
            }
        }

        if (st < 3) {
            // in-place z update: wave-private row, all window reads already done
#pragma unroll
            for (int pt = 0; pt < 8; ++pt) {
                if (q < 2) {
                    union { h4 v; fp16x2 h[2]; } zv;
                    zv.h[0] = __builtin_amdgcn_cvt_pkrtz(acc2[pt][0], acc2[pt][1]);
                    zv.h[1] = __builtin_amdgcn_cvt_pkrtz(acc2[pt][2], acc2[pt][3]);
                    *(h4*)((char*)zwp + pt * 256) = zv.v;
                    if (pt == 0 && p16 < 2)                       // pairs 0,1 -> 130,131
                        *(h4*)((char*)zwp + pt * 256 + 2048) = zv.v;
                    if (pt == 7 && p16 >= 14)                     // pairs 126,127 -> 0,1
                        *(h4*)((char*)zwp + pt * 256 - 2048) = zv.v;
                }
            }
        } else {
#pragma unroll
            for (int pt = 0; pt < 8; ++pt) {
                if (q < 2) *(f4*)(op + pt * 128) = acc2[pt];
            }
        }
    }
}

extern "C" void kernel_launch(void* const* d_in, const int* in_sizes, int n_in,
                              void* d_out, int out_size, void* d_ws, size_t ws_size,
                              hipStream_t stream) {
    const float* x  = (const float*)d_in[0];
    const float* Wi = (const float*)d_in[1];
    const float* bi = (const float*)d_in[2];
    const float* Wo = (const float*)d_in[3];
    float* out = (float*)d_out;

    h8* Wi16 = (h8*)d_ws;                           // 12288 h8 = 196608 B
    h4* Wo2m = (h4*)((char*)d_ws + 196608);         // 4096 h4  = 32768 B
    float* rowsum = (float*)((char*)d_ws + 229376); // 64 f32   = 256 B

    prep_all<<<65, 256, 0, stream>>>(Wi, bi, Wo, Wi16, Wo2m, rowsum);

    int nrows = in_sizes[0] / D_;                   // 4096
    ldrfm10<<<nrows / 4, 256, 0, stream>>>(x, Wi16, Wo2m, rowsum, out);
}